// Round 3
// baseline (284.858 us; speedup 1.0000x reference)
//
#include <hip/hip_runtime.h>
#include <hip/hip_bf16.h>

typedef __attribute__((ext_vector_type(8))) short short8;
typedef __attribute__((ext_vector_type(4))) short short4v;
typedef __attribute__((ext_vector_type(4))) float floatx4;

#define BB 8
#define CC 256
#define ICH 128
#define TT 4096
#define SS 2048
static constexpr float BN_EPS = 1e-5f;
static constexpr float INV_S  = 1.0f / 2048.0f;
static constexpr float INV_BT = 1.0f / 32768.0f;   // 1/(B*T)

// ---------------------------------------------------------------------------
// k0x: transpose + convert  x[b][c][t] (f32)  ->  xt[b][t][c] (bf16)
// grid (64 t-tiles, 4 c-tiles, 8 b), block 256, tile 64x64
// ---------------------------------------------------------------------------
__global__ __launch_bounds__(256) void k0x_transpose(
    const float* __restrict__ x, __hip_bfloat16* __restrict__ xt)
{
    __shared__ float Tl[64][65];
    const int b = blockIdx.z, cb = blockIdx.y * 64, tb = blockIdx.x * 64;
    const int tid = threadIdx.x;
    #pragma unroll
    for (int it = 0; it < 4; ++it) {
        int idx = tid + 256 * it;
        int row = idx >> 4, c4 = idx & 15;
        float4 v = *(const float4*)(x + ((size_t)b * CC + cb + row) * TT + tb + c4 * 4);
        Tl[row][c4 * 4 + 0] = v.x; Tl[row][c4 * 4 + 1] = v.y;
        Tl[row][c4 * 4 + 2] = v.z; Tl[row][c4 * 4 + 3] = v.w;
    }
    __syncthreads();
    #pragma unroll
    for (int it = 0; it < 2; ++it) {
        int idx = tid + 256 * it;
        int trow = idx >> 3, ch = idx & 7;
        alignas(16) __hip_bfloat16 tmp[8];
        #pragma unroll
        for (int e = 0; e < 8; ++e) tmp[e] = __float2bfloat16(Tl[ch * 8 + e][trow]);
        *(short8*)(xt + ((size_t)b * TT + tb + trow) * CC + cb + ch * 8) = *(const short8*)tmp;
    }
}

// ---------------------------------------------------------------------------
// k0w: convert phi_w,g_w -> stacked bf16 Wf[256][256]
// ---------------------------------------------------------------------------
__global__ __launch_bounds__(256) void k0w_conv(
    const float* __restrict__ phi_w, const float* __restrict__ g_w,
    __hip_bfloat16* __restrict__ Wf)
{
    int idx = blockIdx.x * 256 + threadIdx.x;       // 0..16383, 4 floats each
    const float* src = (idx < 8192) ? (phi_w + (size_t)idx * 4)
                                    : (g_w + (size_t)(idx - 8192) * 4);
    float4 v = *(const float4*)src;
    alignas(8) __hip_bfloat16 t[4];
    t[0] = __float2bfloat16(v.x); t[1] = __float2bfloat16(v.y);
    t[2] = __float2bfloat16(v.z); t[3] = __float2bfloat16(v.w);
    *(short4v*)(Wf + (size_t)idx * 4) = *(const short4v*)t;
}

// ---------------------------------------------------------------------------
// k1: barrier-free MFMA conv1x1 (stacked phi|g) + maxpool2.
// Direct-from-global fragments (no LDS). Wave = 64 o x 32 pooled s.
// Block = 4 waves covering o=256; grid (64 s-tiles of 32, 8 b).
// Pool pairs mapped to even/odd column tiles -> lane-local fmax.
// ---------------------------------------------------------------------------
__global__ __launch_bounds__(256) void k1_mfma(
    const __hip_bfloat16* __restrict__ Wf, const float* __restrict__ phi_b,
    const float* __restrict__ g_b, const __hip_bfloat16* __restrict__ xt,
    __hip_bfloat16* __restrict__ phi_g)
{
    const int b  = blockIdx.y;
    const int s0 = blockIdx.x * 32;       // pooled output base
    const int tb = s0 * 2;                // pre-pool t base
    const int tid = threadIdx.x;
    const int w = tid >> 6, l = tid & 63;
    const int quad = l >> 4, lm = l & 15;
    const int m0 = w * 64;

    const __hip_bfloat16* Abase = Wf + ((size_t)(m0 + lm)) * CC + quad * 8;
    const __hip_bfloat16* Bbase = xt + ((size_t)b * TT + tb + 2 * lm) * CC + quad * 8;

    floatx4 acc[4][4];
    #pragma unroll
    for (int i = 0; i < 4; ++i)
        #pragma unroll
        for (int j = 0; j < 4; ++j) acc[i][j] = (floatx4)0.f;

    #pragma unroll
    for (int ks = 0; ks < 8; ++ks) {
        short8 a[4], bb[4];
        #pragma unroll
        for (int i = 0; i < 4; ++i)
            a[i] = *(const short8*)(Abase + (size_t)(i * 16) * CC + ks * 32);
        #pragma unroll
        for (int u = 0; u < 2; ++u)
            #pragma unroll
            for (int p = 0; p < 2; ++p)
                bb[2 * u + p] = *(const short8*)(Bbase + (size_t)(u * 32 + p) * CC + ks * 32);
        #pragma unroll
        for (int i = 0; i < 4; ++i)
            #pragma unroll
            for (int j = 0; j < 4; ++j)
                acc[i][j] = __builtin_amdgcn_mfma_f32_16x16x32_bf16(a[i], bb[j], acc[i][j], 0, 0, 0);
    }

    // epilogue: lane-local pool of even/odd tiles, +bias, direct bf16 store
    #pragma unroll
    for (int i = 0; i < 4; ++i) {
        #pragma unroll
        for (int r = 0; r < 4; ++r) {
            int o = m0 + i * 16 + quad * 4 + r;
            float bias = (o < ICH) ? phi_b[o] : g_b[o - ICH];
            #pragma unroll
            for (int u = 0; u < 2; ++u) {
                float v = fmaxf(acc[i][2 * u][r], acc[i][2 * u + 1][r]) + bias;
                phi_g[((size_t)b * CC + o) * SS + s0 + u * 16 + lm] = __float2bfloat16(v);
            }
        }
    }
}

// ---------------------------------------------------------------------------
// k2: barrier-free MFMA Gram partials
//   Mpart[b][sc][c'][c] = sum_{s in 128-chunk sc} phi[c'][s] * g[c][s]
// Block = 4 waves (2x2 of 64x64) -> full 128x128; grid (16 sc, 8 b).
// ---------------------------------------------------------------------------
__global__ __launch_bounds__(256) void k2_mfma(
    const __hip_bfloat16* __restrict__ phi_g, float* __restrict__ Mpart)
{
    const int sc = blockIdx.x, b = blockIdx.y;
    const int tid = threadIdx.x;
    const int w = tid >> 6, l = tid & 63;
    const int quad = l >> 4, lm = l & 15;
    const int wm = (w & 1) * 64, wn = (w >> 1) * 64;

    const __hip_bfloat16* Abase = phi_g + ((size_t)b * CC + wm + lm) * SS + sc * 128 + quad * 8;
    const __hip_bfloat16* Bbase = phi_g + ((size_t)b * CC + ICH + wn + lm) * SS + sc * 128 + quad * 8;

    floatx4 acc[4][4];
    #pragma unroll
    for (int i = 0; i < 4; ++i)
        #pragma unroll
        for (int j = 0; j < 4; ++j) acc[i][j] = (floatx4)0.f;

    #pragma unroll
    for (int ks = 0; ks < 4; ++ks) {
        short8 a[4], bb[4];
        #pragma unroll
        for (int i = 0; i < 4; ++i)
            a[i] = *(const short8*)(Abase + (size_t)(i * 16) * SS + ks * 32);
        #pragma unroll
        for (int j = 0; j < 4; ++j)
            bb[j] = *(const short8*)(Bbase + (size_t)(j * 16) * SS + ks * 32);
        #pragma unroll
        for (int i = 0; i < 4; ++i)
            #pragma unroll
            for (int j = 0; j < 4; ++j)
                acc[i][j] = __builtin_amdgcn_mfma_f32_16x16x32_bf16(a[i], bb[j], acc[i][j], 0, 0, 0);
    }

    float* dst = Mpart + ((size_t)(b * 16 + sc) * ICH) * ICH;
    #pragma unroll
    for (int i = 0; i < 4; ++i)
        #pragma unroll
        for (int j = 0; j < 4; ++j)
            #pragma unroll
            for (int r = 0; r < 4; ++r)
                dst[(size_t)(wm + i * 16 + quad * 4 + r) * ICH + wn + j * 16 + lm] = acc[i][j][r];
}

// ---------------------------------------------------------------------------
// k3a: Kb[b][co][c'] = (1/S) * sum_c w_w[co][c] * M[b][c'][c]  (M = sum of 16 partials)
// ---------------------------------------------------------------------------
__global__ __launch_bounds__(256) void k3a_kb(
    const float* __restrict__ w_w, const float* __restrict__ Mpart,
    float* __restrict__ Kb)
{
    __shared__ float Al[64][65];
    __shared__ float Bl[64][65];
    const int b = blockIdx.z;
    const int cob = blockIdx.y * 64;
    const int cpb = blockIdx.x * 64;
    const int tid = threadIdx.x;
    const int tx = tid & 15, ty = tid >> 4;

    float acc[4][4] = {};
    for (int kc2 = 0; kc2 < 2; ++kc2) {
        #pragma unroll
        for (int r = 0; r < 4; ++r) {
            int idx = tid + 256 * r;
            int row = idx >> 4, c4 = idx & 15;
            float4 v = *(const float4*)(w_w + (size_t)(cob + row) * ICH + kc2 * 64 + c4 * 4);
            Al[c4 * 4 + 0][row] = v.x; Al[c4 * 4 + 1][row] = v.y;
            Al[c4 * 4 + 2][row] = v.z; Al[c4 * 4 + 3][row] = v.w;
        }
        #pragma unroll
        for (int r = 0; r < 4; ++r) {
            int idx = tid + 256 * r;
            int row = idx >> 4, c4 = idx & 15;
            float4 s = {0.f, 0.f, 0.f, 0.f};
            for (int kc = 0; kc < 16; ++kc) {
                float4 v = *(const float4*)(Mpart + (((size_t)b * 16 + kc) * ICH + cpb + row) * ICH + kc2 * 64 + c4 * 4);
                s.x += v.x; s.y += v.y; s.z += v.z; s.w += v.w;
            }
            Bl[c4 * 4 + 0][row] = s.x; Bl[c4 * 4 + 1][row] = s.y;
            Bl[c4 * 4 + 2][row] = s.z; Bl[c4 * 4 + 3][row] = s.w;
        }
        __syncthreads();
        for (int k = 0; k < 64; ++k) {
            float av[4], bv[4];
            #pragma unroll
            for (int i = 0; i < 4; ++i) av[i] = Al[k][ty + 16 * i];
            #pragma unroll
            for (int j = 0; j < 4; ++j) bv[j] = Bl[k][tx + 16 * j];
            #pragma unroll
            for (int i = 0; i < 4; ++i)
                #pragma unroll
                for (int j = 0; j < 4; ++j) acc[i][j] += av[i] * bv[j];
        }
        __syncthreads();
    }
    #pragma unroll
    for (int i = 0; i < 4; ++i)
        #pragma unroll
        for (int j = 0; j < 4; ++j)
            Kb[((size_t)b * CC + cob + ty + 16 * i) * ICH + cpb + tx + 16 * j] = acc[i][j] * INV_S;
}

// ---------------------------------------------------------------------------
// k3b: P[b][co][ci] = sum_{c'} Kb[b][co][c'] * theta_w[c'][ci]   (bf16 output)
// ---------------------------------------------------------------------------
__global__ __launch_bounds__(256) void k3b_p(
    const float* __restrict__ Kb, const float* __restrict__ theta_w,
    __hip_bfloat16* __restrict__ P)
{
    __shared__ float Al[64][65];
    __shared__ float Bl[64][128];
    const int b = blockIdx.z;
    const int cob = blockIdx.y * 64;
    const int cib = blockIdx.x * 128;
    const int tid = threadIdx.x;
    const int tx = tid & 15, ty = tid >> 4;

    float acc[4][8] = {};
    for (int kc2 = 0; kc2 < 2; ++kc2) {
        #pragma unroll
        for (int r = 0; r < 4; ++r) {
            int idx = tid + 256 * r;
            int row = idx >> 4, c4 = idx & 15;
            float4 v = *(const float4*)(Kb + ((size_t)b * CC + cob + row) * ICH + kc2 * 64 + c4 * 4);
            Al[c4 * 4 + 0][row] = v.x; Al[c4 * 4 + 1][row] = v.y;
            Al[c4 * 4 + 2][row] = v.z; Al[c4 * 4 + 3][row] = v.w;
        }
        #pragma unroll
        for (int r = 0; r < 8; ++r) {
            int idx = tid + 256 * r;
            int row = idx >> 5, c4 = idx & 31;
            *(float4*)(&Bl[row][c4 * 4]) =
                *(const float4*)(theta_w + (size_t)(kc2 * 64 + row) * CC + cib + c4 * 4);
        }
        __syncthreads();
        for (int k = 0; k < 64; ++k) {
            float av[4], bv[8];
            #pragma unroll
            for (int i = 0; i < 4; ++i) av[i] = Al[k][ty + 16 * i];
            #pragma unroll
            for (int j = 0; j < 8; ++j) bv[j] = Bl[k][tx + 16 * j];
            #pragma unroll
            for (int i = 0; i < 4; ++i)
                #pragma unroll
                for (int j = 0; j < 8; ++j) acc[i][j] += av[i] * bv[j];
        }
        __syncthreads();
    }
    #pragma unroll
    for (int i = 0; i < 4; ++i)
        #pragma unroll
        for (int j = 0; j < 8; ++j)
            P[((size_t)b * CC + cob + ty + 16 * i) * CC + cib + tx + 16 * j] =
                __float2bfloat16(acc[i][j]);
}

// ---------------------------------------------------------------------------
// k3c: q[b][co] = w_b[co] + sum_{c'} Kb[b][co][c'] * theta_b[c']
// ---------------------------------------------------------------------------
__global__ __launch_bounds__(256) void k3c_q(
    const float* __restrict__ Kb, const float* __restrict__ theta_b,
    const float* __restrict__ w_b, float* __restrict__ q)
{
    __shared__ float tbs[ICH];
    const int b = blockIdx.x, co = threadIdx.x;
    if (co < ICH) tbs[co] = theta_b[co];
    __syncthreads();
    const float* kr = Kb + ((size_t)b * CC + co) * ICH;
    float s = w_b[co];
    for (int c = 0; c < ICH; ++c) s += kr[c] * tbs[c];
    q[b * CC + co] = s;
}

// ---------------------------------------------------------------------------
// k4: barrier-free MFMA  wy[b][c][t] = sum_ci P[b][c][ci] * xt[b][t][ci] + q
//     Direct-from-global fragments. Wave = 64 m x 64 t; block = 4 waves
//     covering m=256; grid (64 t-tiles of 64, 8 b). + BN partial stats.
// ---------------------------------------------------------------------------
__global__ __launch_bounds__(256) void k4_mfma(
    const __hip_bfloat16* __restrict__ P, const __hip_bfloat16* __restrict__ xt,
    const float* __restrict__ q, __hip_bfloat16* __restrict__ wy,
    float* __restrict__ stats)
{
    const int b  = blockIdx.y;
    const int t0 = blockIdx.x * 64;
    const int tid = threadIdx.x;
    const int w = tid >> 6, l = tid & 63;
    const int quad = l >> 4, lm = l & 15;
    const int m0 = w * 64;

    const __hip_bfloat16* Abase = P + ((size_t)b * CC + m0 + lm) * CC + quad * 8;
    const __hip_bfloat16* Bbase = xt + ((size_t)b * TT + t0 + lm) * CC + quad * 8;

    floatx4 acc[4][4];
    #pragma unroll
    for (int i = 0; i < 4; ++i)
        #pragma unroll
        for (int j = 0; j < 4; ++j) acc[i][j] = (floatx4)0.f;

    #pragma unroll
    for (int ks = 0; ks < 8; ++ks) {
        short8 a[4], bb[4];
        #pragma unroll
        for (int i = 0; i < 4; ++i)
            a[i] = *(const short8*)(Abase + (size_t)(i * 16) * CC + ks * 32);
        #pragma unroll
        for (int j = 0; j < 4; ++j)
            bb[j] = *(const short8*)(Bbase + (size_t)(j * 16) * CC + ks * 32);
        #pragma unroll
        for (int i = 0; i < 4; ++i)
            #pragma unroll
            for (int j = 0; j < 4; ++j)
                acc[i][j] = __builtin_amdgcn_mfma_f32_16x16x32_bf16(a[i], bb[j], acc[i][j], 0, 0, 0);
    }

    // epilogue: +q bias, BN partial stats, direct bf16 store
    #pragma unroll
    for (int i = 0; i < 4; ++i) {
        #pragma unroll
        for (int r = 0; r < 4; ++r) {
            int m = m0 + i * 16 + quad * 4 + r;
            float bias = q[b * CC + m];
            float s1 = 0.f, s2 = 0.f;
            #pragma unroll
            for (int j = 0; j < 4; ++j) {
                float v = acc[i][j][r] + bias;
                s1 += v; s2 += v * v;
                wy[((size_t)b * CC + m) * TT + t0 + j * 16 + lm] = __float2bfloat16(v);
            }
            #pragma unroll
            for (int off = 1; off < 16; off <<= 1) {
                s1 += __shfl_xor(s1, off);
                s2 += __shfl_xor(s2, off);
            }
            if (lm == 0) {
                atomicAdd(&stats[m], s1);
                atomicAdd(&stats[CC + m], s2);
            }
        }
    }
}

// ---------------------------------------------------------------------------
// k5: BN coefficients
// ---------------------------------------------------------------------------
__global__ void k5_bn(const float* __restrict__ stats, const float* __restrict__ gamma,
                      const float* __restrict__ beta, float* __restrict__ coef)
{
    int c = threadIdx.x;
    float mean = stats[c] * INV_BT;
    float var  = stats[CC + c] * INV_BT - mean * mean;
    float A = gamma[c] * rsqrtf(var + BN_EPS);
    coef[c] = A;
    coef[CC + c] = beta[c] - mean * A;
}

// ---------------------------------------------------------------------------
// k6: out = wy_bf16 * A[c] + B[c] + x   (8 elems/thread)
// ---------------------------------------------------------------------------
__global__ __launch_bounds__(256) void k6_out(
    const __hip_bfloat16* __restrict__ wy, const float* __restrict__ x,
    const float* __restrict__ coef, float* __restrict__ out)
{
    size_t idx = (size_t)blockIdx.x * 256 + threadIdx.x;   // 1,048,576 threads
    int c = (int)((idx >> 9) & 255);                       // 512 chunks of 8 per row
    float A = coef[c], Bc = coef[CC + c];
    short8 wv = *(const short8*)(wy + idx * 8);
    const __hip_bfloat16* wb = (const __hip_bfloat16*)&wv;
    const float4* xp = (const float4*)(x + idx * 8);
    float4 x0 = xp[0], x1 = xp[1];
    float4 o0, o1;
    o0.x = __bfloat162float(wb[0]) * A + Bc + x0.x;
    o0.y = __bfloat162float(wb[1]) * A + Bc + x0.y;
    o0.z = __bfloat162float(wb[2]) * A + Bc + x0.z;
    o0.w = __bfloat162float(wb[3]) * A + Bc + x0.w;
    o1.x = __bfloat162float(wb[4]) * A + Bc + x1.x;
    o1.y = __bfloat162float(wb[5]) * A + Bc + x1.y;
    o1.z = __bfloat162float(wb[6]) * A + Bc + x1.z;
    o1.w = __bfloat162float(wb[7]) * A + Bc + x1.w;
    float4* op = (float4*)(out + idx * 8);
    op[0] = o0; op[1] = o1;
}

extern "C" void kernel_launch(void* const* d_in, const int* in_sizes, int n_in,
                              void* d_out, int out_size, void* d_ws, size_t ws_size,
                              hipStream_t stream)
{
    const float* x        = (const float*)d_in[0];
    const float* theta_w  = (const float*)d_in[1];
    const float* theta_b  = (const float*)d_in[2];
    const float* phi_w    = (const float*)d_in[3];
    const float* phi_b    = (const float*)d_in[4];
    const float* g_w      = (const float*)d_in[5];
    const float* g_b      = (const float*)d_in[6];
    const float* w_w      = (const float*)d_in[7];
    const float* w_b      = (const float*)d_in[8];
    const float* bn_gamma = (const float*)d_in[9];
    const float* bn_beta  = (const float*)d_in[10];
    float* out = (float*)d_out;

    char* p = (char*)d_ws;
    __hip_bfloat16* xt    = (__hip_bfloat16*)p; p += (size_t)8388608 * 2;   // [8][4096][256]
    __hip_bfloat16* Wf    = (__hip_bfloat16*)p; p += (size_t)65536 * 2;     // [256][256]
    __hip_bfloat16* phi_g = (__hip_bfloat16*)p; p += (size_t)4194304 * 2;   // [8][256][2048]
    __hip_bfloat16* P     = (__hip_bfloat16*)p; p += (size_t)524288 * 2;    // [8][256][256]
    float* Mpart = (float*)p; p += (size_t)2097152 * 4;                     // [8][16][128][128]
    float* Kb    = (float*)p; p += (size_t)262144 * 4;                      // [8][256][128]
    float* q     = (float*)p; p += (size_t)2048 * 4;                        // [8][256]
    __hip_bfloat16* wy = (__hip_bfloat16*)p; p += (size_t)8388608 * 2;      // [8][256][4096]
    float* stats = (float*)p; p += (size_t)512 * 4;
    float* coef  = (float*)p;

    hipMemsetAsync(stats, 0, 512 * sizeof(float), stream);

    k0x_transpose<<<dim3(64, 4, 8), 256, 0, stream>>>(x, xt);
    k0w_conv<<<dim3(64), 256, 0, stream>>>(phi_w, g_w, Wf);
    k1_mfma<<<dim3(64, 8), 256, 0, stream>>>(Wf, phi_b, g_b, xt, phi_g);
    k2_mfma<<<dim3(16, 8), 256, 0, stream>>>(phi_g, Mpart);
    k3a_kb<<<dim3(2, 4, 8), 256, 0, stream>>>(w_w, Mpart, Kb);
    k3b_p<<<dim3(2, 4, 8), 256, 0, stream>>>(Kb, theta_w, P);
    k3c_q<<<dim3(8), 256, 0, stream>>>(Kb, theta_b, w_b, q);
    k4_mfma<<<dim3(64, 8), 256, 0, stream>>>(P, xt, q, wy, stats);
    k5_bn<<<dim3(1), 256, 0, stream>>>(stats, bn_gamma, bn_beta, coef);
    k6_out<<<dim3(4096), 256, 0, stream>>>(wy, x, coef, out);
}

// Round 4
// 235.519 us; speedup vs baseline: 1.2095x; 1.2095x over previous
//
#include <hip/hip_runtime.h>
#include <hip/hip_bf16.h>

typedef __attribute__((ext_vector_type(8))) short short8;
typedef __attribute__((ext_vector_type(4))) short short4v;
typedef __attribute__((ext_vector_type(4))) float floatx4;
typedef unsigned int u32;

#define BB 8
#define CC 256
#define ICH 128
#define TT 4096
#define SS 2048
static constexpr float BN_EPS = 1e-5f;
static constexpr float INV_S  = 1.0f / 2048.0f;
static constexpr float INV_BT = 1.0f / 32768.0f;   // 1/(B*T)

// async global->LDS DMA, 16 B per lane; LDS dest = wave-uniform base + lane*16
typedef const __attribute__((address_space(1))) u32* gas_ptr;
typedef __attribute__((address_space(3))) u32* las_ptr;
__device__ __forceinline__ void gl_lds16(const void* g, void* l) {
    __builtin_amdgcn_global_load_lds((gas_ptr)g, (las_ptr)l, 16, 0, 0);
}

// ---------------------------------------------------------------------------
// k0x: transpose + convert  x[b][c][t] (f32)  ->  xt[b][t][c] (bf16)
// ---------------------------------------------------------------------------
__global__ __launch_bounds__(256) void k0x_transpose(
    const float* __restrict__ x, __hip_bfloat16* __restrict__ xt)
{
    __shared__ float Tl[64][65];
    const int b = blockIdx.z, cb = blockIdx.y * 64, tb = blockIdx.x * 64;
    const int tid = threadIdx.x;
    #pragma unroll
    for (int it = 0; it < 4; ++it) {
        int idx = tid + 256 * it;
        int row = idx >> 4, c4 = idx & 15;
        float4 v = *(const float4*)(x + ((size_t)b * CC + cb + row) * TT + tb + c4 * 4);
        Tl[row][c4 * 4 + 0] = v.x; Tl[row][c4 * 4 + 1] = v.y;
        Tl[row][c4 * 4 + 2] = v.z; Tl[row][c4 * 4 + 3] = v.w;
    }
    __syncthreads();
    #pragma unroll
    for (int it = 0; it < 2; ++it) {
        int idx = tid + 256 * it;
        int trow = idx >> 3, ch = idx & 7;
        alignas(16) __hip_bfloat16 tmp[8];
        #pragma unroll
        for (int e = 0; e < 8; ++e) tmp[e] = __float2bfloat16(Tl[ch * 8 + e][trow]);
        *(short8*)(xt + ((size_t)b * TT + tb + trow) * CC + cb + ch * 8) = *(const short8*)tmp;
    }
}

// ---------------------------------------------------------------------------
// k0w: convert phi_w,g_w -> stacked bf16 Wf[256][256]
// ---------------------------------------------------------------------------
__global__ __launch_bounds__(256) void k0w_conv(
    const float* __restrict__ phi_w, const float* __restrict__ g_w,
    __hip_bfloat16* __restrict__ Wf)
{
    int idx = blockIdx.x * 256 + threadIdx.x;
    const float* src = (idx < 8192) ? (phi_w + (size_t)idx * 4)
                                    : (g_w + (size_t)(idx - 8192) * 4);
    float4 v = *(const float4*)src;
    alignas(8) __hip_bfloat16 t[4];
    t[0] = __float2bfloat16(v.x); t[1] = __float2bfloat16(v.y);
    t[2] = __float2bfloat16(v.z); t[3] = __float2bfloat16(v.w);
    *(short4v*)(Wf + (size_t)idx * 4) = *(const short4v*)t;
}

// ---------------------------------------------------------------------------
// k1: m97-style MFMA conv1x1 (stacked phi|g) + maxpool2 epilogue.
// 128x128 tile, BK=64, global_load_lds staging, ds_read_b128 fragments.
// grid (32 pre-pool t-tiles of 128, 2 m-tiles, 8 b), block 256 (4 waves)
// ---------------------------------------------------------------------------
__global__ __launch_bounds__(256) void k1_mfma(
    const __hip_bfloat16* __restrict__ Wf, const float* __restrict__ phi_b,
    const float* __restrict__ g_b, const __hip_bfloat16* __restrict__ xt,
    __hip_bfloat16* __restrict__ phi_g)
{
    __shared__ short lds[2 * 128 * 64];   // As | Bs, 32 KB
    short* As = lds;
    short* Bs = lds + 128 * 64;

    const int b  = blockIdx.z;
    const int m0 = blockIdx.y * 128;
    const int tb = blockIdx.x * 128;      // pre-pool t base
    const int s0 = blockIdx.x * 64;       // pooled output base
    const int tid = threadIdx.x;
    const int w = tid >> 6, l = tid & 63;
    const int quad = l >> 4, lm = l & 15;
    const int wm = (w & 1) * 64, wn = (w >> 1) * 64;
    const int rs = l >> 3, cs = (l & 7) * 8;   // staging row-sub / col

    const __hip_bfloat16* Ap = Wf + (size_t)m0 * CC;
    const __hip_bfloat16* Bp = xt + ((size_t)b * TT + tb) * CC;

    floatx4 acc[4][4];
    #pragma unroll
    for (int i = 0; i < 4; ++i)
        #pragma unroll
        for (int j = 0; j < 4; ++j) acc[i][j] = (floatx4)0.f;

    for (int kc = 0; kc < 4; ++kc) {
        const int k0 = kc * 64;
        const int rbase = w * 32;
        #pragma unroll
        for (int t = 0; t < 4; ++t) {
            gl_lds16(Ap + (size_t)(rbase + t * 8 + rs) * CC + k0 + cs, &As[(rbase + t * 8) * 64]);
            gl_lds16(Bp + (size_t)(rbase + t * 8 + rs) * CC + k0 + cs, &Bs[(rbase + t * 8) * 64]);
        }
        __syncthreads();
        #pragma unroll
        for (int ks = 0; ks < 2; ++ks) {
            short8 a[4], bb[4];
            #pragma unroll
            for (int i = 0; i < 4; ++i)
                a[i] = *(const short8*)&As[(wm + i * 16 + lm) * 64 + ks * 32 + quad * 8];
            #pragma unroll
            for (int j = 0; j < 4; ++j)
                bb[j] = *(const short8*)&Bs[(wn + j * 16 + lm) * 64 + ks * 32 + quad * 8];
            #pragma unroll
            for (int i = 0; i < 4; ++i)
                #pragma unroll
                for (int j = 0; j < 4; ++j)
                    acc[i][j] = __builtin_amdgcn_mfma_f32_16x16x32_bf16(a[i], bb[j], acc[i][j], 0, 0, 0);
        }
        __syncthreads();
    }

    // epilogue: stage pre-pool bf16 tile, then pool pairs + bias, wide stores
    __hip_bfloat16* Out = (__hip_bfloat16*)lds;   // 128 x 128 bf16 = 32 KB
    #pragma unroll
    for (int i = 0; i < 4; ++i)
        #pragma unroll
        for (int j = 0; j < 4; ++j)
            #pragma unroll
            for (int r = 0; r < 4; ++r)
                Out[(wm + i * 16 + quad * 4 + r) * 128 + wn + j * 16 + lm] =
                    __float2bfloat16(acc[i][j][r]);
    __syncthreads();
    #pragma unroll
    for (int it = 0; it < 4; ++it) {
        int idx = tid + 256 * it;
        int orow = idx >> 3, grp = idx & 7;
        int o = m0 + orow;
        float bias = (o < ICH) ? phi_b[o] : g_b[o - ICH];
        short8 v0 = *(const short8*)&Out[orow * 128 + grp * 16];
        short8 v1 = *(const short8*)&Out[orow * 128 + grp * 16 + 8];
        const __hip_bfloat16* p0 = (const __hip_bfloat16*)&v0;
        const __hip_bfloat16* p1 = (const __hip_bfloat16*)&v1;
        alignas(16) __hip_bfloat16 o8[8];
        #pragma unroll
        for (int e = 0; e < 4; ++e)
            o8[e] = __float2bfloat16(
                fmaxf(__bfloat162float(p0[2 * e]), __bfloat162float(p0[2 * e + 1])) + bias);
        #pragma unroll
        for (int e = 0; e < 4; ++e)
            o8[4 + e] = __float2bfloat16(
                fmaxf(__bfloat162float(p1[2 * e]), __bfloat162float(p1[2 * e + 1])) + bias);
        *(short8*)(phi_g + ((size_t)b * CC + o) * SS + s0 + grp * 8) = *(const short8*)o8;
    }
}

// ---------------------------------------------------------------------------
// k2: m97-style MFMA Gram partials
//   Mpart[b][sc][c'][c] = sum_{s in 64-chunk sc} phi[c'][s] * g[c][s]
// grid (32 sc, 8 b), block 256 (4 waves, full 128x128 output), single BK=64
// ---------------------------------------------------------------------------
__global__ __launch_bounds__(256) void k2_mfma(
    const __hip_bfloat16* __restrict__ phi_g, float* __restrict__ Mpart)
{
    __shared__ short lds[2 * 128 * 64];
    short* As = lds;
    short* Bs = lds + 128 * 64;
    const int sc = blockIdx.x, b = blockIdx.y;
    const int tid = threadIdx.x;
    const int w = tid >> 6, l = tid & 63;
    const int quad = l >> 4, lm = l & 15;
    const int wm = (w & 1) * 64, wn = (w >> 1) * 64;
    const int rs = l >> 3, cs = (l & 7) * 8;

    const __hip_bfloat16* Ap = phi_g + (size_t)b * CC * SS + sc * 64;        // phi rows
    const __hip_bfloat16* Bp = Ap + (size_t)ICH * SS;                         // g rows

    {
        const int rbase = w * 32;
        #pragma unroll
        for (int t = 0; t < 4; ++t) {
            gl_lds16(Ap + (size_t)(rbase + t * 8 + rs) * SS + cs, &As[(rbase + t * 8) * 64]);
            gl_lds16(Bp + (size_t)(rbase + t * 8 + rs) * SS + cs, &Bs[(rbase + t * 8) * 64]);
        }
    }
    __syncthreads();

    floatx4 acc[4][4];
    #pragma unroll
    for (int i = 0; i < 4; ++i)
        #pragma unroll
        for (int j = 0; j < 4; ++j) acc[i][j] = (floatx4)0.f;

    #pragma unroll
    for (int ks = 0; ks < 2; ++ks) {
        short8 a[4], bb[4];
        #pragma unroll
        for (int i = 0; i < 4; ++i)
            a[i] = *(const short8*)&As[(wm + i * 16 + lm) * 64 + ks * 32 + quad * 8];
        #pragma unroll
        for (int j = 0; j < 4; ++j)
            bb[j] = *(const short8*)&Bs[(wn + j * 16 + lm) * 64 + ks * 32 + quad * 8];
        #pragma unroll
        for (int i = 0; i < 4; ++i)
            #pragma unroll
            for (int j = 0; j < 4; ++j)
                acc[i][j] = __builtin_amdgcn_mfma_f32_16x16x32_bf16(a[i], bb[j], acc[i][j], 0, 0, 0);
    }

    float* dst = Mpart + ((size_t)(b * 32 + sc)) * ICH * ICH;
    #pragma unroll
    for (int i = 0; i < 4; ++i)
        #pragma unroll
        for (int j = 0; j < 4; ++j)
            #pragma unroll
            for (int r = 0; r < 4; ++r)
                dst[(size_t)(wm + i * 16 + quad * 4 + r) * ICH + wn + j * 16 + lm] = acc[i][j][r];
}

// ---------------------------------------------------------------------------
// k3a: Kb[b][co][c'] = (1/S) * sum_c w_w[co][c] * M[b][c'][c]  (sum of 32 partials)
// ---------------------------------------------------------------------------
__global__ __launch_bounds__(256) void k3a_kb(
    const float* __restrict__ w_w, const float* __restrict__ Mpart,
    float* __restrict__ Kb)
{
    __shared__ float Al[64][65];
    __shared__ float Bl[64][65];
    const int b = blockIdx.z;
    const int cob = blockIdx.y * 64;
    const int cpb = blockIdx.x * 64;
    const int tid = threadIdx.x;
    const int tx = tid & 15, ty = tid >> 4;

    float acc[4][4] = {};
    for (int kc2 = 0; kc2 < 2; ++kc2) {
        #pragma unroll
        for (int r = 0; r < 4; ++r) {
            int idx = tid + 256 * r;
            int row = idx >> 4, c4 = idx & 15;
            float4 v = *(const float4*)(w_w + (size_t)(cob + row) * ICH + kc2 * 64 + c4 * 4);
            Al[c4 * 4 + 0][row] = v.x; Al[c4 * 4 + 1][row] = v.y;
            Al[c4 * 4 + 2][row] = v.z; Al[c4 * 4 + 3][row] = v.w;
        }
        #pragma unroll
        for (int r = 0; r < 4; ++r) {
            int idx = tid + 256 * r;
            int row = idx >> 4, c4 = idx & 15;
            float4 s = {0.f, 0.f, 0.f, 0.f};
            for (int kc = 0; kc < 32; ++kc) {
                float4 v = *(const float4*)(Mpart + (((size_t)b * 32 + kc) * ICH + cpb + row) * ICH + kc2 * 64 + c4 * 4);
                s.x += v.x; s.y += v.y; s.z += v.z; s.w += v.w;
            }
            Bl[c4 * 4 + 0][row] = s.x; Bl[c4 * 4 + 1][row] = s.y;
            Bl[c4 * 4 + 2][row] = s.z; Bl[c4 * 4 + 3][row] = s.w;
        }
        __syncthreads();
        for (int k = 0; k < 64; ++k) {
            float av[4], bv[4];
            #pragma unroll
            for (int i = 0; i < 4; ++i) av[i] = Al[k][ty + 16 * i];
            #pragma unroll
            for (int j = 0; j < 4; ++j) bv[j] = Bl[k][tx + 16 * j];
            #pragma unroll
            for (int i = 0; i < 4; ++i)
                #pragma unroll
                for (int j = 0; j < 4; ++j) acc[i][j] += av[i] * bv[j];
        }
        __syncthreads();
    }
    #pragma unroll
    for (int i = 0; i < 4; ++i)
        #pragma unroll
        for (int j = 0; j < 4; ++j)
            Kb[((size_t)b * CC + cob + ty + 16 * i) * ICH + cpb + tx + 16 * j] = acc[i][j] * INV_S;
}

// ---------------------------------------------------------------------------
// k3b: P[b][co][ci] = sum_{c'} Kb[b][co][c'] * theta_w[c'][ci]   (bf16 output)
// ---------------------------------------------------------------------------
__global__ __launch_bounds__(256) void k3b_p(
    const float* __restrict__ Kb, const float* __restrict__ theta_w,
    __hip_bfloat16* __restrict__ P)
{
    __shared__ float Al[64][65];
    __shared__ float Bl[64][128];
    const int b = blockIdx.z;
    const int cob = blockIdx.y * 64;
    const int cib = blockIdx.x * 128;
    const int tid = threadIdx.x;
    const int tx = tid & 15, ty = tid >> 4;

    float acc[4][8] = {};
    for (int kc2 = 0; kc2 < 2; ++kc2) {
        #pragma unroll
        for (int r = 0; r < 4; ++r) {
            int idx = tid + 256 * r;
            int row = idx >> 4, c4 = idx & 15;
            float4 v = *(const float4*)(Kb + ((size_t)b * CC + cob + row) * ICH + kc2 * 64 + c4 * 4);
            Al[c4 * 4 + 0][row] = v.x; Al[c4 * 4 + 1][row] = v.y;
            Al[c4 * 4 + 2][row] = v.z; Al[c4 * 4 + 3][row] = v.w;
        }
        #pragma unroll
        for (int r = 0; r < 8; ++r) {
            int idx = tid + 256 * r;
            int row = idx >> 5, c4 = idx & 31;
            *(float4*)(&Bl[row][c4 * 4]) =
                *(const float4*)(theta_w + (size_t)(kc2 * 64 + row) * CC + cib + c4 * 4);
        }
        __syncthreads();
        for (int k = 0; k < 64; ++k) {
            float av[4], bv[8];
            #pragma unroll
            for (int i = 0; i < 4; ++i) av[i] = Al[k][ty + 16 * i];
            #pragma unroll
            for (int j = 0; j < 8; ++j) bv[j] = Bl[k][tx + 16 * j];
            #pragma unroll
            for (int i = 0; i < 4; ++i)
                #pragma unroll
                for (int j = 0; j < 8; ++j) acc[i][j] += av[i] * bv[j];
        }
        __syncthreads();
    }
    #pragma unroll
    for (int i = 0; i < 4; ++i)
        #pragma unroll
        for (int j = 0; j < 8; ++j)
            P[((size_t)b * CC + cob + ty + 16 * i) * CC + cib + tx + 16 * j] =
                __float2bfloat16(acc[i][j]);
}

// ---------------------------------------------------------------------------
// k3c: q[b][co] = w_b[co] + sum_{c'} Kb[b][co][c'] * theta_b[c']
// ---------------------------------------------------------------------------
__global__ __launch_bounds__(256) void k3c_q(
    const float* __restrict__ Kb, const float* __restrict__ theta_b,
    const float* __restrict__ w_b, float* __restrict__ q)
{
    __shared__ float tbs[ICH];
    const int b = blockIdx.x, co = threadIdx.x;
    if (co < ICH) tbs[co] = theta_b[co];
    __syncthreads();
    const float* kr = Kb + ((size_t)b * CC + co) * ICH;
    float s = w_b[co];
    for (int c = 0; c < ICH; ++c) s += kr[c] * tbs[c];
    q[b * CC + co] = s;
}

// ---------------------------------------------------------------------------
// k4: m97-style MFMA  wy[b][c][t] = sum_ci P[b][c][ci] * xt[b][t][ci] + q[b][c]
// 128x128 tile, BK=64, global_load_lds staging; no stats here.
// grid (32 t-tiles, 2 m-tiles, 8 b), block 256
// ---------------------------------------------------------------------------
__global__ __launch_bounds__(256) void k4_mfma(
    const __hip_bfloat16* __restrict__ P, const __hip_bfloat16* __restrict__ xt,
    const float* __restrict__ q, __hip_bfloat16* __restrict__ wy)
{
    __shared__ short lds[2 * 128 * 64];
    short* As = lds;
    short* Bs = lds + 128 * 64;

    const int b  = blockIdx.z;
    const int m0 = blockIdx.y * 128;
    const int t0 = blockIdx.x * 128;
    const int tid = threadIdx.x;
    const int w = tid >> 6, l = tid & 63;
    const int quad = l >> 4, lm = l & 15;
    const int wm = (w & 1) * 64, wn = (w >> 1) * 64;
    const int rs = l >> 3, cs = (l & 7) * 8;

    const __hip_bfloat16* Ap = P + ((size_t)b * CC + m0) * CC;
    const __hip_bfloat16* Bp = xt + ((size_t)b * TT + t0) * CC;

    floatx4 acc[4][4];
    #pragma unroll
    for (int i = 0; i < 4; ++i)
        #pragma unroll
        for (int j = 0; j < 4; ++j) acc[i][j] = (floatx4)0.f;

    for (int kc = 0; kc < 4; ++kc) {
        const int k0 = kc * 64;
        const int rbase = w * 32;
        #pragma unroll
        for (int t = 0; t < 4; ++t) {
            gl_lds16(Ap + (size_t)(rbase + t * 8 + rs) * CC + k0 + cs, &As[(rbase + t * 8) * 64]);
            gl_lds16(Bp + (size_t)(rbase + t * 8 + rs) * CC + k0 + cs, &Bs[(rbase + t * 8) * 64]);
        }
        __syncthreads();
        #pragma unroll
        for (int ks = 0; ks < 2; ++ks) {
            short8 a[4], bb[4];
            #pragma unroll
            for (int i = 0; i < 4; ++i)
                a[i] = *(const short8*)&As[(wm + i * 16 + lm) * 64 + ks * 32 + quad * 8];
            #pragma unroll
            for (int j = 0; j < 4; ++j)
                bb[j] = *(const short8*)&Bs[(wn + j * 16 + lm) * 64 + ks * 32 + quad * 8];
            #pragma unroll
            for (int i = 0; i < 4; ++i)
                #pragma unroll
                for (int j = 0; j < 4; ++j)
                    acc[i][j] = __builtin_amdgcn_mfma_f32_16x16x32_bf16(a[i], bb[j], acc[i][j], 0, 0, 0);
        }
        __syncthreads();
    }

    // epilogue: +q bias, LDS-stage bf16 tile, coalesced wide stores
    __hip_bfloat16* Out = (__hip_bfloat16*)lds;   // 128 x 128 bf16 = 32 KB
    #pragma unroll
    for (int i = 0; i < 4; ++i) {
        #pragma unroll
        for (int r = 0; r < 4; ++r) {
            int m = wm + i * 16 + quad * 4 + r;
            float bias = q[b * CC + m0 + m];
            #pragma unroll
            for (int j = 0; j < 4; ++j)
                Out[m * 128 + wn + j * 16 + lm] = __float2bfloat16(acc[i][j][r] + bias);
        }
    }
    __syncthreads();
    #pragma unroll
    for (int it = 0; it < 8; ++it) {
        int idx = tid + 256 * it;
        int row = idx >> 4, cg = idx & 15;
        *(short8*)(wy + ((size_t)b * CC + m0 + row) * TT + t0 + cg * 8) =
            *(const short8*)&Out[row * 128 + cg * 8];
    }
}

// ---------------------------------------------------------------------------
// k4b: BN stats + coefficients fused. One block per channel c:
//      sum over b,t of wy[b][c][:], then coef[c]=A, coef[256+c]=B.
// ---------------------------------------------------------------------------
__global__ __launch_bounds__(256) void k4b_stats(
    const __hip_bfloat16* __restrict__ wy, const float* __restrict__ gamma,
    const float* __restrict__ beta, float* __restrict__ coef)
{
    const int c = blockIdx.x;
    const int tid = threadIdx.x;
    float s1 = 0.f, s2 = 0.f;
    for (int b = 0; b < BB; ++b) {
        const __hip_bfloat16* row = wy + ((size_t)b * CC + c) * TT;
        #pragma unroll
        for (int i = 0; i < 2; ++i) {
            short8 v = *(const short8*)(row + (size_t)(tid + 256 * i) * 8);
            const __hip_bfloat16* pv = (const __hip_bfloat16*)&v;
            #pragma unroll
            for (int e = 0; e < 8; ++e) {
                float f = __bfloat162float(pv[e]);
                s1 += f; s2 += f * f;
            }
        }
    }
    #pragma unroll
    for (int off = 1; off < 64; off <<= 1) {
        s1 += __shfl_xor(s1, off);
        s2 += __shfl_xor(s2, off);
    }
    __shared__ float r1[4], r2[4];
    if ((tid & 63) == 0) { r1[tid >> 6] = s1; r2[tid >> 6] = s2; }
    __syncthreads();
    if (tid == 0) {
        float t1 = r1[0] + r1[1] + r1[2] + r1[3];
        float t2 = r2[0] + r2[1] + r2[2] + r2[3];
        float mean = t1 * INV_BT;
        float var  = t2 * INV_BT - mean * mean;
        float A = gamma[c] * rsqrtf(var + BN_EPS);
        coef[c] = A;
        coef[CC + c] = beta[c] - mean * A;
    }
}

// ---------------------------------------------------------------------------
// k6: out = wy_bf16 * A[c] + B[c] + x   (8 elems/thread)
// ---------------------------------------------------------------------------
__global__ __launch_bounds__(256) void k6_out(
    const __hip_bfloat16* __restrict__ wy, const float* __restrict__ x,
    const float* __restrict__ coef, float* __restrict__ out)
{
    size_t idx = (size_t)blockIdx.x * 256 + threadIdx.x;
    int c = (int)((idx >> 9) & 255);
    float A = coef[c], Bc = coef[CC + c];
    short8 wv = *(const short8*)(wy + idx * 8);
    const __hip_bfloat16* wb = (const __hip_bfloat16*)&wv;
    const float4* xp = (const float4*)(x + idx * 8);
    float4 x0 = xp[0], x1 = xp[1];
    float4 o0, o1;
    o0.x = __bfloat162float(wb[0]) * A + Bc + x0.x;
    o0.y = __bfloat162float(wb[1]) * A + Bc + x0.y;
    o0.z = __bfloat162float(wb[2]) * A + Bc + x0.z;
    o0.w = __bfloat162float(wb[3]) * A + Bc + x0.w;
    o1.x = __bfloat162float(wb[4]) * A + Bc + x1.x;
    o1.y = __bfloat162float(wb[5]) * A + Bc + x1.y;
    o1.z = __bfloat162float(wb[6]) * A + Bc + x1.z;
    o1.w = __bfloat162float(wb[7]) * A + Bc + x1.w;
    float4* op = (float4*)(out + idx * 8);
    op[0] = o0; op[1] = o1;
}

extern "C" void kernel_launch(void* const* d_in, const int* in_sizes, int n_in,
                              void* d_out, int out_size, void* d_ws, size_t ws_size,
                              hipStream_t stream)
{
    const float* x        = (const float*)d_in[0];
    const float* theta_w  = (const float*)d_in[1];
    const float* theta_b  = (const float*)d_in[2];
    const float* phi_w    = (const float*)d_in[3];
    const float* phi_b    = (const float*)d_in[4];
    const float* g_w      = (const float*)d_in[5];
    const float* g_b      = (const float*)d_in[6];
    const float* w_w      = (const float*)d_in[7];
    const float* w_b      = (const float*)d_in[8];
    const float* bn_gamma = (const float*)d_in[9];
    const float* bn_beta  = (const float*)d_in[10];
    float* out = (float*)d_out;

    char* p = (char*)d_ws;
    __hip_bfloat16* xt    = (__hip_bfloat16*)p; p += (size_t)8388608 * 2;   // [8][4096][256]
    __hip_bfloat16* Wf    = (__hip_bfloat16*)p; p += (size_t)65536 * 2;     // [256][256]
    __hip_bfloat16* phi_g = (__hip_bfloat16*)p; p += (size_t)4194304 * 2;   // [8][256][2048]
    __hip_bfloat16* P     = (__hip_bfloat16*)p; p += (size_t)524288 * 2;    // [8][256][256]
    float* Mpart = (float*)p; p += (size_t)4194304 * 4;                     // [8][32][128][128]
    float* Kb    = (float*)p; p += (size_t)262144 * 4;                      // [8][256][128]
    float* q     = (float*)p; p += (size_t)2048 * 4;                        // [8][256]
    __hip_bfloat16* wy = (__hip_bfloat16*)p; p += (size_t)8388608 * 2;      // [8][256][4096]
    float* coef  = (float*)p;                                               // [2][256]

    k0x_transpose<<<dim3(64, 4, 8), 256, 0, stream>>>(x, xt);
    k0w_conv<<<dim3(64), 256, 0, stream>>>(phi_w, g_w, Wf);
    k1_mfma<<<dim3(32, 2, 8), 256, 0, stream>>>(Wf, phi_b, g_b, xt, phi_g);
    k2_mfma<<<dim3(32, 8), 256, 0, stream>>>(phi_g, Mpart);
    k3a_kb<<<dim3(2, 4, 8), 256, 0, stream>>>(w_w, Mpart, Kb);
    k3b_p<<<dim3(2, 4, 8), 256, 0, stream>>>(Kb, theta_w, P);
    k3c_q<<<dim3(8), 256, 0, stream>>>(Kb, theta_b, w_b, q);
    k4_mfma<<<dim3(32, 2, 8), 256, 0, stream>>>(P, xt, q, wy);
    k4b_stats<<<dim3(256), 256, 0, stream>>>(wy, bn_gamma, bn_beta, coef);
    k6_out<<<dim3(4096), 256, 0, stream>>>(wy, x, coef, out);
}